// Round 2
// baseline (657.575 us; speedup 1.0000x reference)
//
#include <hip/hip_runtime.h>

typedef unsigned short u16;
typedef __attribute__((ext_vector_type(8))) unsigned short u16x8;
typedef __attribute__((ext_vector_type(8))) short s16x8;
typedef __attribute__((ext_vector_type(4))) float f32x4;

__device__ __forceinline__ float bf2f(u16 v) {
    return __uint_as_float(((unsigned int)v) << 16);
}
__device__ __forceinline__ u16 f2bf(float f) {
    unsigned int u = __float_as_uint(f);
    return (u16)((u + 0x7FFFu + ((u >> 16) & 1u)) >> 16);
}

// ---------------------------------------------------------------------------
// 1) f32 -> bf16 convert (hidden_states), 8 elems/thread
// ---------------------------------------------------------------------------
__global__ __launch_bounds__(256) void cvt_bf16_kernel(const float* __restrict__ src,
                                                       u16* __restrict__ dst, int n8) {
    int i = blockIdx.x * 256 + threadIdx.x;
    if (i >= n8) return;
    const float4* s4 = (const float4*)src;
    float4 a = s4[i * 2];
    float4 b = s4[i * 2 + 1];
    u16x8 o;
    o[0] = f2bf(a.x); o[1] = f2bf(a.y); o[2] = f2bf(a.z); o[3] = f2bf(a.w);
    o[4] = f2bf(b.x); o[5] = f2bf(b.y); o[6] = f2bf(b.z); o[7] = f2bf(b.w);
    *(u16x8*)(dst + (size_t)i * 8) = o;
}

// ---------------------------------------------------------------------------
// 2) transpose + convert: W (K x N) f32  ->  WT (N x K) bf16
// ---------------------------------------------------------------------------
__global__ __launch_bounds__(256) void tcvt_kernel(const float* __restrict__ src,
                                                   u16* __restrict__ dst, int K, int N) {
    __shared__ float T[32][33];
    int k0 = blockIdx.x * 32, n0 = blockIdx.y * 32;
    int r = threadIdx.x >> 5, c = threadIdx.x & 31;
#pragma unroll
    for (int it = 0; it < 4; ++it)
        T[it * 8 + r][c] = src[(size_t)(k0 + it * 8 + r) * N + n0 + c];
    __syncthreads();
#pragma unroll
    for (int it = 0; it < 4; ++it)
        dst[(size_t)(n0 + it * 8 + r) * K + k0 + c] = f2bf(T[c][it * 8 + r]);
}

// ---------------------------------------------------------------------------
// 3) LoRA adapt virtual KV:  out = X + s * ((X @ A) @ B), write bf16
//    K -> k_full[h][r][d]   (rows 0..63 of the concat K)
//    V -> v_t[h][d][r]      (transposed V layout)
// ---------------------------------------------------------------------------
__global__ __launch_bounds__(128) void lora_kv_kernel(
    const float* __restrict__ vk, const float* __restrict__ vv,
    const float* __restrict__ kA, const float* __restrict__ kB,
    const float* __restrict__ vA, const float* __restrict__ vB,
    const float* __restrict__ skp, const float* __restrict__ svp,
    u16* __restrict__ k_full, u16* __restrict__ v_t) {
    __shared__ float row[128];
    __shared__ float tv[16];
    int h = blockIdx.x >> 6, r = blockIdx.x & 63;
    int d = threadIdx.x;

    // K path
    row[d] = vk[(size_t)(h * 64 + r) * 128 + d];
    __syncthreads();
    if (d < 16) {
        float acc = 0.f;
        for (int i = 0; i < 128; ++i) acc += row[i] * kA[i * 16 + d];
        tv[d] = acc;
    }
    __syncthreads();
    float acc = 0.f;
#pragma unroll
    for (int j = 0; j < 16; ++j) acc += tv[j] * kB[j * 128 + d];
    float outk = row[d] + skp[0] * acc;
    k_full[((size_t)h * 2112 + r) * 128 + d] = f2bf(outk);
    __syncthreads();

    // V path
    row[d] = vv[(size_t)(h * 64 + r) * 128 + d];
    __syncthreads();
    if (d < 16) {
        float a2 = 0.f;
        for (int i = 0; i < 128; ++i) a2 += row[i] * vA[i * 16 + d];
        tv[d] = a2;
    }
    __syncthreads();
    float a3 = 0.f;
#pragma unroll
    for (int j = 0; j < 16; ++j) a3 += tv[j] * vB[j * 128 + d];
    float outv = row[d] + svp[0] * a3;
    v_t[((size_t)h * 128 + d) * 2112 + r] = f2bf(outv);
}

// ---------------------------------------------------------------------------
// 4) bf16 GEMM:  C[M x N] = A[M x K] * B'[N x K]^T   (B' is row-major N x K)
//    128x128 tile, BK=32, 4 waves (2x2), 4x4 16x16x32 MFMA frags per wave.
//    OF32=0 -> bf16 C, OF32=1 -> f32 C.
// ---------------------------------------------------------------------------
template <int OF32>
__global__ __launch_bounds__(256) void gemm_bt_kernel(const u16* __restrict__ A,
                                                      const u16* __restrict__ B,
                                                      void* __restrict__ Cv,
                                                      int M, int N, int K, int ldc) {
    __shared__ u16 As[128][40];
    __shared__ u16 Bs[128][40];
    int tid = threadIdx.x;
    int w = tid >> 6, l = tid & 63, lr = l & 15, lg = l >> 4;
    int m0 = blockIdx.x * 128, n0 = blockIdx.y * 128;
    int wr = (w >> 1) * 64, wc = (w & 1) * 64;
    int trow = tid >> 2, tcol = (tid & 3) * 8;

    const u16* Ag = A + (size_t)(m0 + trow) * K + tcol;
    const u16* Bg = B + (size_t)(n0 + trow) * K + tcol;

    u16x8 ra0 = *(const u16x8*)Ag;
    u16x8 ra1 = *(const u16x8*)(Ag + (size_t)64 * K);
    u16x8 rb0 = *(const u16x8*)Bg;
    u16x8 rb1 = *(const u16x8*)(Bg + (size_t)64 * K);

    f32x4 acc[4][4] = {};
    int NT = K >> 5;
    for (int kt = 0; kt < NT; ++kt) {
        __syncthreads();
        *(u16x8*)&As[trow][tcol] = ra0;
        *(u16x8*)&As[trow + 64][tcol] = ra1;
        *(u16x8*)&Bs[trow][tcol] = rb0;
        *(u16x8*)&Bs[trow + 64][tcol] = rb1;
        if (kt + 1 < NT) {
            int kb = (kt + 1) * 32;
            ra0 = *(const u16x8*)(Ag + kb);
            ra1 = *(const u16x8*)(Ag + kb + (size_t)64 * K);
            rb0 = *(const u16x8*)(Bg + kb);
            rb1 = *(const u16x8*)(Bg + kb + (size_t)64 * K);
        }
        __syncthreads();
        s16x8 af[4], bfr[4];
#pragma unroll
        for (int m = 0; m < 4; ++m) af[m] = *(const s16x8*)&As[wr + m * 16 + lr][lg * 8];
#pragma unroll
        for (int n = 0; n < 4; ++n) bfr[n] = *(const s16x8*)&Bs[wc + n * 16 + lr][lg * 8];
#pragma unroll
        for (int m = 0; m < 4; ++m)
#pragma unroll
            for (int n = 0; n < 4; ++n)
                acc[m][n] = __builtin_amdgcn_mfma_f32_16x16x32_bf16(af[m], bfr[n], acc[m][n], 0, 0, 0);
    }

#pragma unroll
    for (int m = 0; m < 4; ++m)
#pragma unroll
        for (int n = 0; n < 4; ++n)
#pragma unroll
            for (int j = 0; j < 4; ++j) {
                int row = m0 + wr + m * 16 + lg * 4 + j;
                int col = n0 + wc + n * 16 + lr;
                float v = acc[m][n][j];
                if (OF32)
                    ((float*)Cv)[(size_t)row * ldc + col] = v;
                else
                    ((u16*)Cv)[(size_t)row * ldc + col] = f2bf(v);
            }
}

// ---------------------------------------------------------------------------
// 5) Q: per-head RMSNorm + RoPE + attn-scale.  One wave per (t, h).
// ---------------------------------------------------------------------------
__global__ __launch_bounds__(256) void qnorm_rope_kernel(const u16* __restrict__ qkv,
                                                         const float* __restrict__ qw,
                                                         const float* __restrict__ cosb,
                                                         const float* __restrict__ sinb,
                                                         u16* __restrict__ qf) {
    int w = threadIdx.x >> 6, l = threadIdx.x & 63;
    int idx = blockIdx.x * 4 + w;
    int t = idx >> 5, h = idx & 31;
    const u16* src = qkv + (size_t)t * 6144 + h * 128;
    float x1 = bf2f(src[l]), x2 = bf2f(src[l + 64]);
    float ss = x1 * x1 + x2 * x2;
#pragma unroll
    for (int d = 1; d < 64; d <<= 1) ss += __shfl_xor(ss, d, 64);
    float rinv = rsqrtf(ss * (1.0f / 128.0f) + 1e-6f);
    float y1 = x1 * rinv * qw[l], y2 = x2 * rinv * qw[l + 64];
    float c1 = cosb[t * 128 + l], s1 = sinb[t * 128 + l];
    float c2 = cosb[t * 128 + l + 64], s2 = sinb[t * 128 + l + 64];
    const float sc = 0.08838834764831845f;  // 128^-0.5
    u16* dst = qf + (size_t)t * 4096 + h * 128;
    dst[l] = f2bf((y1 * c1 - y2 * s1) * sc);
    dst[l + 64] = f2bf((y2 * c2 + y1 * s2) * sc);
}

// ---------------------------------------------------------------------------
// 6) K: RMSNorm + RoPE -> k_full[h][64+t][d];  V: transpose -> v_t[h][d][64+t]
//    Block handles one (h, 32-row t-tile).
// ---------------------------------------------------------------------------
__global__ __launch_bounds__(256) void kvnorm_rope_kernel(const u16* __restrict__ qkv,
                                                          const float* __restrict__ kw,
                                                          const float* __restrict__ cosb,
                                                          const float* __restrict__ sinb,
                                                          u16* __restrict__ k_full,
                                                          u16* __restrict__ v_t) {
    __shared__ u16 VT[32][136];
    int h = blockIdx.x >> 6;
    int t0 = (blockIdx.x & 63) * 32;
    int tid = threadIdx.x;
    int w = tid >> 6, l = tid & 63;

    // --- K rows: 4 waves x 8 rows ---
    for (int it = 0; it < 8; ++it) {
        int t = t0 + w * 8 + it;
        const u16* src = qkv + (size_t)t * 6144 + 4096 + h * 128;
        float x1 = bf2f(src[l]), x2 = bf2f(src[l + 64]);
        float ss = x1 * x1 + x2 * x2;
#pragma unroll
        for (int d = 1; d < 64; d <<= 1) ss += __shfl_xor(ss, d, 64);
        float rinv = rsqrtf(ss * (1.0f / 128.0f) + 1e-6f);
        float y1 = x1 * rinv * kw[l], y2 = x2 * rinv * kw[l + 64];
        float c1 = cosb[t * 128 + l], s1 = sinb[t * 128 + l];
        float c2 = cosb[t * 128 + l + 64], s2 = sinb[t * 128 + l + 64];
        u16* dst = k_full + ((size_t)h * 2112 + 64 + t) * 128;
        dst[l] = f2bf(y1 * c1 - y2 * s1);
        dst[l + 64] = f2bf(y2 * c2 + y1 * s2);
    }

    // --- V transpose via LDS tile ---
    {
        int tr = tid >> 3, c0 = (tid & 7) * 16;
        const u16* src = qkv + (size_t)(t0 + tr) * 6144 + 5120 + h * 128 + c0;
        *(u16x8*)&VT[tr][c0] = *(const u16x8*)src;
        *(u16x8*)&VT[tr][c0 + 8] = *(const u16x8*)(src + 8);
    }
    __syncthreads();
    {
        int d = tid >> 1, th = (tid & 1) * 16;
        u16x8 a, b;
#pragma unroll
        for (int i = 0; i < 8; ++i) { a[i] = VT[th + i][d]; b[i] = VT[th + 8 + i][d]; }
        u16* dst = v_t + ((size_t)h * 128 + d) * 2112 + 64 + t0 + th;
        *(u16x8*)dst = a;
        *(u16x8*)(dst + 8) = b;
    }
}

// ---------------------------------------------------------------------------
// 7) Flash attention: block = (head h, 64-row q tile), 4 waves x 16 q rows.
//    kv tiles of 64 over [0, q0+128) (virtual 64 + causal reach), analytic mask.
// ---------------------------------------------------------------------------
__global__ __launch_bounds__(256) void attn_kernel(const u16* __restrict__ qf,
                                                   const u16* __restrict__ k_full,
                                                   const u16* __restrict__ v_t,
                                                   u16* __restrict__ attn_out) {
    __shared__ u16 Ks[64][136];   // [kv][d]
    __shared__ u16 Vs[128][72];   // [d][kv]
    __shared__ u16 Pw[4][16][72]; // per-wave P tile [q][kv]

    int h = blockIdx.x >> 5;
    int qt = 31 - (blockIdx.x & 31);  // heavy q-tiles dispatched first
    int q0 = qt * 64;
    int kvh = h >> 2;
    int tid = threadIdx.x, w = tid >> 6, l = tid & 63;
    int lr = l & 15, lg = l >> 4;

    // Q fragments (already attn-scaled)
    s16x8 qfr[4];
    const u16* qbase = qf + (size_t)(q0 + w * 16 + lr) * 4096 + h * 128 + lg * 8;
#pragma unroll
    for (int ks = 0; ks < 4; ++ks) qfr[ks] = *(const s16x8*)(qbase + ks * 32);

    f32x4 o[8] = {};
    float mrun[4], lrun[4];
#pragma unroll
    for (int j = 0; j < 4; ++j) { mrun[j] = -1e30f; lrun[j] = 0.f; }

    int nt = q0 / 64 + 2;
    const u16* Kg = k_full + (size_t)kvh * 2112 * 128;
    const u16* Vg = v_t + (size_t)kvh * 128 * 2112;

    for (int tile = 0; tile < nt; ++tile) {
        int kv0 = tile * 64;
        __syncthreads();
        // stage K tile 64x128
#pragma unroll
        for (int c = 0; c < 4; ++c) {
            int kk = tid + c * 256;
            int row = kk >> 4, col = (kk & 15) * 8;
            *(u16x8*)&Ks[row][col] = *(const u16x8*)(Kg + (size_t)(kv0 + row) * 128 + col);
        }
        // stage V^T tile 128x64
#pragma unroll
        for (int c = 0; c < 4; ++c) {
            int kk = tid + c * 256;
            int row = kk >> 3, col = (kk & 7) * 8;
            *(u16x8*)&Vs[row][col] = *(const u16x8*)(Vg + (size_t)row * 2112 + kv0 + col);
        }
        __syncthreads();

        // S = Q K^T  (16 MFMA / wave)
        f32x4 s[4] = {};
#pragma unroll
        for (int ks = 0; ks < 4; ++ks) {
#pragma unroll
            for (int n = 0; n < 4; ++n) {
                s16x8 b = *(const s16x8*)&Ks[n * 16 + lr][ks * 32 + lg * 8];
                s[n] = __builtin_amdgcn_mfma_f32_16x16x32_bf16(qfr[ks], b, s[n], 0, 0, 0);
            }
        }

        // causal mask: only the last tile can contain masked entries
        if (tile == nt - 1) {
#pragma unroll
            for (int n = 0; n < 4; ++n) {
                int kvi = kv0 + n * 16 + lr;
                if (kvi >= 64) {
                    int kreal = kvi - 64;
#pragma unroll
                    for (int j = 0; j < 4; ++j) {
                        int qi = q0 + w * 16 + lg * 4 + j;
                        if (kreal > qi) s[n][j] = -1e30f;
                    }
                }
            }
        }

        // online softmax (rows j, 16-lane groups)
#pragma unroll
        for (int j = 0; j < 4; ++j) {
            float mx = fmaxf(fmaxf(s[0][j], s[1][j]), fmaxf(s[2][j], s[3][j]));
            mx = fmaxf(mx, __shfl_xor(mx, 1, 64));
            mx = fmaxf(mx, __shfl_xor(mx, 2, 64));
            mx = fmaxf(mx, __shfl_xor(mx, 4, 64));
            mx = fmaxf(mx, __shfl_xor(mx, 8, 64));
            float mnew = fmaxf(mrun[j], mx);
            float scl = __expf(mrun[j] - mnew);
            mrun[j] = mnew;
            lrun[j] *= scl;
#pragma unroll
            for (int nf = 0; nf < 8; ++nf) o[nf][j] *= scl;
            float psum = 0.f;
#pragma unroll
            for (int n = 0; n < 4; ++n) {
                float p = __expf(s[n][j] - mnew);
                s[n][j] = p;
                psum += p;
            }
            lrun[j] += psum;
        }

        // P -> per-wave LDS (re-layout for PV A-operand)
#pragma unroll
        for (int n = 0; n < 4; ++n)
#pragma unroll
            for (int j = 0; j < 4; ++j)
                Pw[w][lg * 4 + j][n * 16 + lr] = f2bf(s[n][j]);

        // O += P V   (16 MFMA / wave)
#pragma unroll
        for (int ks2 = 0; ks2 < 2; ++ks2) {
            s16x8 pa = *(const s16x8*)&Pw[w][lr][ks2 * 32 + lg * 8];
#pragma unroll
            for (int nf = 0; nf < 8; ++nf) {
                s16x8 vb = *(const s16x8*)&Vs[nf * 16 + lr][ks2 * 32 + lg * 8];
                o[nf] = __builtin_amdgcn_mfma_f32_16x16x32_bf16(pa, vb, o[nf], 0, 0, 0);
            }
        }
    }

    // epilogue: normalize rows, write bf16
    float rinv[4];
#pragma unroll
    for (int j = 0; j < 4; ++j) {
        float ls = lrun[j];
        ls += __shfl_xor(ls, 1, 64);
        ls += __shfl_xor(ls, 2, 64);
        ls += __shfl_xor(ls, 4, 64);
        ls += __shfl_xor(ls, 8, 64);
        rinv[j] = 1.0f / ls;
    }
#pragma unroll
    for (int nf = 0; nf < 8; ++nf)
#pragma unroll
        for (int j = 0; j < 4; ++j) {
            int row = q0 + w * 16 + lg * 4 + j;
            int col = h * 128 + nf * 16 + lr;
            attn_out[(size_t)row * 4096 + col] = f2bf(o[nf][j] * rinv[j]);
        }
}

// ---------------------------------------------------------------------------
// launch
// ---------------------------------------------------------------------------
extern "C" void kernel_launch(void* const* d_in, const int* in_sizes, int n_in,
                              void* d_out, int out_size, void* d_ws, size_t ws_size,
                              hipStream_t stream) {
    const float* hidden = (const float*)d_in[0];
    const float* vkeys = (const float*)d_in[1];
    const float* vvals = (const float*)d_in[2];
    const float* Wq = (const float*)d_in[3];
    const float* Wk = (const float*)d_in[4];
    const float* Wv = (const float*)d_in[5];
    const float* Wo = (const float*)d_in[6];
    const float* qnw = (const float*)d_in[7];
    const float* knw = (const float*)d_in[8];
    const float* lkA = (const float*)d_in[9];
    const float* lkB = (const float*)d_in[10];
    const float* lvA = (const float*)d_in[11];
    const float* lvB = (const float*)d_in[12];
    const float* skp = (const float*)d_in[13];
    const float* svp = (const float*)d_in[14];
    // d_in[15] = attention_mask: analytically causal, not read
    const float* cosb = (const float*)d_in[16];
    const float* sinb = (const float*)d_in[17];

    char* ws = (char*)d_ws;
    u16* hid_bf = (u16*)(ws);                    // 16 MB (reused as attn_out)
    u16* WqT    = (u16*)(ws + 16777216);         // 32 MB, contiguous with WkT/WvT: B' (6144 x 4096)
    u16* WkT    = (u16*)(ws + 50331648);         // 8 MB
    u16* WvT    = (u16*)(ws + 58720256);         // 8 MB
    u16* WoT    = (u16*)(ws + 67108864);         // 32 MB
    u16* qkv    = (u16*)(ws + 100663296);        // 24 MB (2048 x 6144)
    u16* qfin   = (u16*)(ws + 125829120);        // 16 MB (2048 x 4096)
    u16* kfull  = (u16*)(ws + 142606336);        // 4.125 MB (8 x 2112 x 128)
    u16* vt     = (u16*)(ws + 146931712);        // 4.125 MB (8 x 128 x 2112)
    u16* attn_o = hid_bf;                        // alias: hidden_bf dead after proj GEMM

    // converts / transposes
    cvt_bf16_kernel<<<4096, 256, 0, stream>>>(hidden, hid_bf, 1048576);
    tcvt_kernel<<<dim3(128, 128), 256, 0, stream>>>(Wq, WqT, 4096, 4096);
    tcvt_kernel<<<dim3(128, 32), 256, 0, stream>>>(Wk, WkT, 4096, 1024);
    tcvt_kernel<<<dim3(128, 32), 256, 0, stream>>>(Wv, WvT, 4096, 1024);
    tcvt_kernel<<<dim3(128, 128), 256, 0, stream>>>(Wo, WoT, 4096, 4096);

    // LoRA virtual KV
    lora_kv_kernel<<<512, 128, 0, stream>>>(vkeys, vvals, lkA, lkB, lvA, lvB, skp, svp,
                                            kfull, vt);

    // fused QKV projection: (2048 x 4096) x (6144 x 4096)^T -> qkv (bf16)
    gemm_bt_kernel<0><<<dim3(16, 48), 256, 0, stream>>>(hid_bf, WqT, qkv, 2048, 6144, 4096, 6144);

    // norms + rope
    qnorm_rope_kernel<<<16384, 256, 0, stream>>>(qkv, qnw, cosb, sinb, qfin);
    kvnorm_rope_kernel<<<512, 256, 0, stream>>>(qkv, knw, cosb, sinb, kfull, vt);

    // attention
    attn_kernel<<<1024, 256, 0, stream>>>(qfin, kfull, vt, attn_o);

    // output projection: (2048 x 4096) x (4096 x 4096)^T -> d_out (f32)
    gemm_bt_kernel<1><<<dim3(16, 32), 256, 0, stream>>>(attn_o, WoT, d_out, 2048, 4096, 4096, 4096);
}

// Round 3
// 589.359 us; speedup vs baseline: 1.1157x; 1.1157x over previous
//
#include <hip/hip_runtime.h>

typedef unsigned short u16;
typedef __attribute__((ext_vector_type(8))) unsigned short u16x8;
typedef __attribute__((ext_vector_type(8))) short s16x8;
typedef __attribute__((ext_vector_type(4))) float f32x4;

typedef __attribute__((address_space(1))) void gvoid;
typedef __attribute__((address_space(3))) void lvoid;

__device__ __forceinline__ float bf2f(u16 v) {
    return __uint_as_float(((unsigned int)v) << 16);
}
__device__ __forceinline__ u16 f2bf(float f) {
    unsigned int u = __float_as_uint(f);
    return (u16)((u + 0x7FFFu + ((u >> 16) & 1u)) >> 16);
}
__device__ __forceinline__ void gload16(const void* g, void* l) {
    __builtin_amdgcn_global_load_lds((gvoid*)g, (lvoid*)l, 16, 0, 0);
}

// ---------------------------------------------------------------------------
// 1) f32 -> bf16 convert (hidden_states), 8 elems/thread
// ---------------------------------------------------------------------------
__global__ __launch_bounds__(256) void cvt_bf16_kernel(const float* __restrict__ src,
                                                       u16* __restrict__ dst, int n8) {
    int i = blockIdx.x * 256 + threadIdx.x;
    if (i >= n8) return;
    const float4* s4 = (const float4*)src;
    float4 a = s4[i * 2];
    float4 b = s4[i * 2 + 1];
    u16x8 o;
    o[0] = f2bf(a.x); o[1] = f2bf(a.y); o[2] = f2bf(a.z); o[3] = f2bf(a.w);
    o[4] = f2bf(b.x); o[5] = f2bf(b.y); o[6] = f2bf(b.z); o[7] = f2bf(b.w);
    *(u16x8*)(dst + (size_t)i * 8) = o;
}

// ---------------------------------------------------------------------------
// 2) transpose + convert: W (K x N) f32  ->  WT (N x K) bf16
// ---------------------------------------------------------------------------
__global__ __launch_bounds__(256) void tcvt_kernel(const float* __restrict__ src,
                                                   u16* __restrict__ dst, int K, int N) {
    __shared__ float T[32][33];
    int k0 = blockIdx.x * 32, n0 = blockIdx.y * 32;
    int r = threadIdx.x >> 5, c = threadIdx.x & 31;
#pragma unroll
    for (int it = 0; it < 4; ++it)
        T[it * 8 + r][c] = src[(size_t)(k0 + it * 8 + r) * N + n0 + c];
    __syncthreads();
#pragma unroll
    for (int it = 0; it < 4; ++it)
        dst[(size_t)(n0 + it * 8 + r) * K + k0 + c] = f2bf(T[c][it * 8 + r]);
}

// ---------------------------------------------------------------------------
// 3) LoRA adapt virtual KV:  out = X + s * ((X @ A) @ B), write bf16
// ---------------------------------------------------------------------------
__global__ __launch_bounds__(128) void lora_kv_kernel(
    const float* __restrict__ vk, const float* __restrict__ vv,
    const float* __restrict__ kA, const float* __restrict__ kB,
    const float* __restrict__ vA, const float* __restrict__ vB,
    const float* __restrict__ skp, const float* __restrict__ svp,
    u16* __restrict__ k_full, u16* __restrict__ v_t) {
    __shared__ float row[128];
    __shared__ float tv[16];
    int h = blockIdx.x >> 6, r = blockIdx.x & 63;
    int d = threadIdx.x;

    row[d] = vk[(size_t)(h * 64 + r) * 128 + d];
    __syncthreads();
    if (d < 16) {
        float acc = 0.f;
        for (int i = 0; i < 128; ++i) acc += row[i] * kA[i * 16 + d];
        tv[d] = acc;
    }
    __syncthreads();
    float acc = 0.f;
#pragma unroll
    for (int j = 0; j < 16; ++j) acc += tv[j] * kB[j * 128 + d];
    float outk = row[d] + skp[0] * acc;
    k_full[((size_t)h * 2112 + r) * 128 + d] = f2bf(outk);
    __syncthreads();

    row[d] = vv[(size_t)(h * 64 + r) * 128 + d];
    __syncthreads();
    if (d < 16) {
        float a2 = 0.f;
        for (int i = 0; i < 128; ++i) a2 += row[i] * vA[i * 16 + d];
        tv[d] = a2;
    }
    __syncthreads();
    float a3 = 0.f;
#pragma unroll
    for (int j = 0; j < 16; ++j) a3 += tv[j] * vB[j * 128 + d];
    float outv = row[d] + svp[0] * a3;
    v_t[((size_t)h * 128 + d) * 2112 + r] = f2bf(outv);
}

// ---------------------------------------------------------------------------
// 4) bf16 GEMM (m97 structure): C = A[MxK] * B'[NxK]^T, 128x128 tile, BK=32,
//    global_load_lds staging, explicit double-buffer with static buf indices.
// ---------------------------------------------------------------------------
template <int OF32>
__global__ __launch_bounds__(256) void gemm_bt_kernel(const u16* __restrict__ A,
                                                      const u16* __restrict__ B,
                                                      void* __restrict__ Cv,
                                                      int M, int N, int K, int ldc) {
    __shared__ u16 As[2][128][32];
    __shared__ u16 Bs[2][128][32];
    int tid = threadIdx.x;
    int w = tid >> 6, l = tid & 63, lr = l & 15, lg = l >> 4;
    int m0 = blockIdx.x * 128, n0 = blockIdx.y * 128;
    int wr = (w >> 1) * 64, wc = (w & 1) * 64;
    int srow = tid >> 2, scol = (tid & 3) * 8;

    const u16* Ag = A + (size_t)(m0 + srow) * K + scol;
    const u16* Bg = B + (size_t)(n0 + srow) * K + scol;
    size_t rstep = (size_t)64 * K;

    f32x4 acc[4][4] = {};
    int NT = K >> 5;  // assumed even

#define STAGE_G(buf, kt)                                       \
    do {                                                       \
        int koff = (kt) * 32;                                  \
        gload16(Ag + koff, &As[buf][srow][scol]);              \
        gload16(Ag + koff + rstep, &As[buf][srow + 64][scol]); \
        gload16(Bg + koff, &Bs[buf][srow][scol]);              \
        gload16(Bg + koff + rstep, &Bs[buf][srow + 64][scol]); \
    } while (0)

#define COMPUTE_G(buf)                                                                     \
    do {                                                                                   \
        s16x8 af[4], bfr[4];                                                               \
        _Pragma("unroll") for (int m = 0; m < 4; ++m)                                      \
            af[m] = *(const s16x8*)&As[buf][wr + m * 16 + lr][lg * 8];                     \
        _Pragma("unroll") for (int n = 0; n < 4; ++n)                                      \
            bfr[n] = *(const s16x8*)&Bs[buf][wc + n * 16 + lr][lg * 8];                    \
        _Pragma("unroll") for (int m = 0; m < 4; ++m)                                      \
            _Pragma("unroll") for (int n = 0; n < 4; ++n)                                  \
                acc[m][n] = __builtin_amdgcn_mfma_f32_16x16x32_bf16(af[m], bfr[n],         \
                                                                    acc[m][n], 0, 0, 0);  \
    } while (0)

    STAGE_G(0, 0);
    __syncthreads();
    for (int kt = 0; kt < NT; kt += 2) {
        if (kt + 1 < NT) STAGE_G(1, kt + 1);
        COMPUTE_G(0);
        __syncthreads();
        if (kt + 2 < NT) STAGE_G(0, kt + 2);
        COMPUTE_G(1);
        __syncthreads();
    }
#undef STAGE_G
#undef COMPUTE_G

#pragma unroll
    for (int m = 0; m < 4; ++m)
#pragma unroll
        for (int n = 0; n < 4; ++n)
#pragma unroll
            for (int j = 0; j < 4; ++j) {
                int row = m0 + wr + m * 16 + lg * 4 + j;
                int col = n0 + wc + n * 16 + lr;
                float v = acc[m][n][j];
                if (OF32)
                    ((float*)Cv)[(size_t)row * ldc + col] = v;
                else
                    ((u16*)Cv)[(size_t)row * ldc + col] = f2bf(v);
            }
}

// ---------------------------------------------------------------------------
// 5) Q: per-head RMSNorm + RoPE + (attn-scale * log2e).  One wave per (t, h).
// ---------------------------------------------------------------------------
__global__ __launch_bounds__(256) void qnorm_rope_kernel(const u16* __restrict__ qkv,
                                                         const float* __restrict__ qw,
                                                         const float* __restrict__ cosb,
                                                         const float* __restrict__ sinb,
                                                         u16* __restrict__ qf) {
    int w = threadIdx.x >> 6, l = threadIdx.x & 63;
    int idx = blockIdx.x * 4 + w;
    int t = idx >> 5, h = idx & 31;
    const u16* src = qkv + (size_t)t * 6144 + h * 128;
    float x1 = bf2f(src[l]), x2 = bf2f(src[l + 64]);
    float ss = x1 * x1 + x2 * x2;
#pragma unroll
    for (int d = 1; d < 64; d <<= 1) ss += __shfl_xor(ss, d, 64);
    float rinv = rsqrtf(ss * (1.0f / 128.0f) + 1e-6f);
    float y1 = x1 * rinv * qw[l], y2 = x2 * rinv * qw[l + 64];
    float c1 = cosb[t * 128 + l], s1 = sinb[t * 128 + l];
    float c2 = cosb[t * 128 + l + 64], s2 = sinb[t * 128 + l + 64];
    const float sc = 0.08838834764831845f * 1.4426950408889634f;  // 128^-0.5 * log2(e)
    u16* dst = qf + (size_t)t * 4096 + h * 128;
    dst[l] = f2bf((y1 * c1 - y2 * s1) * sc);
    dst[l + 64] = f2bf((y2 * c2 + y1 * s2) * sc);
}

// ---------------------------------------------------------------------------
// 6) K: RMSNorm + RoPE -> k_full[h][64+t][d];  V: transpose -> v_t[h][d][64+t]
// ---------------------------------------------------------------------------
__global__ __launch_bounds__(256) void kvnorm_rope_kernel(const u16* __restrict__ qkv,
                                                          const float* __restrict__ kw,
                                                          const float* __restrict__ cosb,
                                                          const float* __restrict__ sinb,
                                                          u16* __restrict__ k_full,
                                                          u16* __restrict__ v_t) {
    __shared__ u16 VT[32][136];
    int h = blockIdx.x >> 6;
    int t0 = (blockIdx.x & 63) * 32;
    int tid = threadIdx.x;
    int w = tid >> 6, l = tid & 63;

    for (int it = 0; it < 8; ++it) {
        int t = t0 + w * 8 + it;
        const u16* src = qkv + (size_t)t * 6144 + 4096 + h * 128;
        float x1 = bf2f(src[l]), x2 = bf2f(src[l + 64]);
        float ss = x1 * x1 + x2 * x2;
#pragma unroll
        for (int d = 1; d < 64; d <<= 1) ss += __shfl_xor(ss, d, 64);
        float rinv = rsqrtf(ss * (1.0f / 128.0f) + 1e-6f);
        float y1 = x1 * rinv * kw[l], y2 = x2 * rinv * kw[l + 64];
        float c1 = cosb[t * 128 + l], s1 = sinb[t * 128 + l];
        float c2 = cosb[t * 128 + l + 64], s2 = sinb[t * 128 + l + 64];
        u16* dst = k_full + ((size_t)h * 2112 + 64 + t) * 128;
        dst[l] = f2bf(y1 * c1 - y2 * s1);
        dst[l + 64] = f2bf(y2 * c2 + y1 * s2);
    }

    {
        int tr = tid >> 3, c0 = (tid & 7) * 16;
        const u16* src = qkv + (size_t)(t0 + tr) * 6144 + 5120 + h * 128 + c0;
        *(u16x8*)&VT[tr][c0] = *(const u16x8*)src;
        *(u16x8*)&VT[tr][c0 + 8] = *(const u16x8*)(src + 8);
    }
    __syncthreads();
    {
        int d = tid >> 1, th = (tid & 1) * 16;
        u16x8 a, b;
#pragma unroll
        for (int i = 0; i < 8; ++i) { a[i] = VT[th + i][d]; b[i] = VT[th + 8 + i][d]; }
        u16* dst = v_t + ((size_t)h * 128 + d) * 2112 + 64 + t0 + th;
        *(u16x8*)dst = a;
        *(u16x8*)(dst + 8) = b;
    }
}

// ---------------------------------------------------------------------------
// 7) Flash attention.  Block = (head, q-tile PAIR (31-pr, pr)) -> uniform work.
//    4 waves x 16 q rows, kv tiles of 64.  XOR-swizzled LDS (T2), exp2-domain
//    softmax with defer-rescale (T13).  Grid: 32 heads * 16 pairs = 512.
// ---------------------------------------------------------------------------
__global__ __launch_bounds__(256) void attn_kernel(const u16* __restrict__ qf,
                                                   const u16* __restrict__ k_full,
                                                   const u16* __restrict__ v_t,
                                                   u16* __restrict__ attn_out) {
    __shared__ u16 Ks[64][128];   // [kv][d]   swizzled
    __shared__ u16 Vs[128][64];   // [d][kv]   swizzled
    __shared__ u16 Pw[4][16][64]; // per-wave [q][kv] swizzled

    int h = blockIdx.x >> 4;
    int pr = blockIdx.x & 15;
    int kvh = h >> 2;
    int tid = threadIdx.x, w = tid >> 6, l = tid & 63;
    int lr = l & 15, lg = l >> 4;
    const u16* Kg = k_full + (size_t)kvh * 2112 * 128;
    const u16* Vg = v_t + (size_t)kvh * 128 * 2112;

    for (int seg = 0; seg < 2; ++seg) {
        int qt = seg ? pr : 31 - pr;
        int q0 = qt * 64;

        s16x8 qfr[4];
        const u16* qbase = qf + (size_t)(q0 + w * 16 + lr) * 4096 + h * 128 + lg * 8;
#pragma unroll
        for (int ks = 0; ks < 4; ++ks) qfr[ks] = *(const s16x8*)(qbase + ks * 32);

        f32x4 o[8] = {};
        float mrun[4], lrun[4];
#pragma unroll
        for (int j = 0; j < 4; ++j) { mrun[j] = -1e30f; lrun[j] = 0.f; }

        int nt = qt + 2;
        for (int tile = 0; tile < nt; ++tile) {
            int kv0 = tile * 64;
            __syncthreads();
#pragma unroll
            for (int c = 0; c < 4; ++c) {  // K tile 64x128
                int kk = tid + c * 256;
                int row = kk >> 4, col = (kk & 15) * 8;
                *(u16x8*)&Ks[row][col ^ ((row & 7) << 3)] =
                    *(const u16x8*)(Kg + (size_t)(kv0 + row) * 128 + col);
            }
#pragma unroll
            for (int c = 0; c < 4; ++c) {  // V^T tile 128x64
                int kk = tid + c * 256;
                int row = kk >> 3, col = (kk & 7) * 8;
                *(u16x8*)&Vs[row][col ^ ((row & 7) << 3)] =
                    *(const u16x8*)(Vg + (size_t)row * 2112 + kv0 + col);
            }
            __syncthreads();

            // S = Q K^T
            f32x4 s[4] = {};
#pragma unroll
            for (int ks = 0; ks < 4; ++ks) {
#pragma unroll
                for (int n = 0; n < 4; ++n) {
                    s16x8 b = *(const s16x8*)&Ks[n * 16 + lr][(ks * 32 + lg * 8) ^ ((lr & 7) << 3)];
                    s[n] = __builtin_amdgcn_mfma_f32_16x16x32_bf16(qfr[ks], b, s[n], 0, 0, 0);
                }
            }

            if (tile == nt - 1) {  // causal mask, last tile only
#pragma unroll
                for (int n = 0; n < 4; ++n) {
                    int kvi = kv0 + n * 16 + lr;
                    if (kvi >= 64) {
                        int kreal = kvi - 64;
#pragma unroll
                        for (int j = 0; j < 4; ++j) {
                            int qi = q0 + w * 16 + lg * 4 + j;
                            if (kreal > qi) s[n][j] = -1e30f;
                        }
                    }
                }
            }

            // online softmax (exp2 domain; Q was pre-scaled by log2e)
            float tmx[4];
            float growth = -3.0e38f;
#pragma unroll
            for (int j = 0; j < 4; ++j) {
                float mx = fmaxf(fmaxf(s[0][j], s[1][j]), fmaxf(s[2][j], s[3][j]));
                mx = fmaxf(mx, __shfl_xor(mx, 1, 64));
                mx = fmaxf(mx, __shfl_xor(mx, 2, 64));
                mx = fmaxf(mx, __shfl_xor(mx, 4, 64));
                mx = fmaxf(mx, __shfl_xor(mx, 8, 64));
                tmx[j] = mx;
                growth = fmaxf(growth, mx - mrun[j]);
            }
            if (!__all(growth <= 11.5f)) {
#pragma unroll
                for (int j = 0; j < 4; ++j) {
                    float mnew = fmaxf(mrun[j], tmx[j]);
                    float scl = exp2f(mrun[j] - mnew);
                    mrun[j] = mnew;
                    lrun[j] *= scl;
#pragma unroll
                    for (int nf = 0; nf < 8; ++nf) o[nf][j] *= scl;
                }
            }
#pragma unroll
            for (int j = 0; j < 4; ++j) {
                float psum = 0.f;
#pragma unroll
                for (int n = 0; n < 4; ++n) {
                    float p = exp2f(s[n][j] - mrun[j]);
                    s[n][j] = p;
                    psum += p;
                }
                lrun[j] += psum;
            }

            // P -> per-wave LDS (swizzled scalar writes)
#pragma unroll
            for (int n = 0; n < 4; ++n)
#pragma unroll
                for (int j = 0; j < 4; ++j) {
                    int prow = lg * 4 + j;
                    int pcol = n * 16 + lr;
                    int pswz = (pcol & 7) | ((((pcol >> 3) ^ prow) & 7) << 3);
                    Pw[w][prow][pswz] = f2bf(s[n][j]);
                }

            // O += P V
#pragma unroll
            for (int ks2 = 0; ks2 < 2; ++ks2) {
                s16x8 pa = *(const s16x8*)&Pw[w][lr][(ks2 * 32 + lg * 8) ^ ((lr & 7) << 3)];
#pragma unroll
                for (int nf = 0; nf < 8; ++nf) {
                    s16x8 vb = *(const s16x8*)&Vs[nf * 16 + lr][(ks2 * 32 + lg * 8) ^ ((lr & 7) << 3)];
                    o[nf] = __builtin_amdgcn_mfma_f32_16x16x32_bf16(pa, vb, o[nf], 0, 0, 0);
                }
            }
        }

        float rinv[4];
#pragma unroll
        for (int j = 0; j < 4; ++j) {
            float ls = lrun[j];
            ls += __shfl_xor(ls, 1, 64);
            ls += __shfl_xor(ls, 2, 64);
            ls += __shfl_xor(ls, 4, 64);
            ls += __shfl_xor(ls, 8, 64);
            rinv[j] = 1.0f / ls;
        }
#pragma unroll
        for (int nf = 0; nf < 8; ++nf)
#pragma unroll
            for (int j = 0; j < 4; ++j) {
                int row = q0 + w * 16 + lg * 4 + j;
                int col = h * 128 + nf * 16 + lr;
                attn_out[(size_t)row * 4096 + col] = f2bf(o[nf][j] * rinv[j]);
            }
    }
}

// ---------------------------------------------------------------------------
// launch
// ---------------------------------------------------------------------------
extern "C" void kernel_launch(void* const* d_in, const int* in_sizes, int n_in,
                              void* d_out, int out_size, void* d_ws, size_t ws_size,
                              hipStream_t stream) {
    const float* hidden = (const float*)d_in[0];
    const float* vkeys = (const float*)d_in[1];
    const float* vvals = (const float*)d_in[2];
    const float* Wq = (const float*)d_in[3];
    const float* Wk = (const float*)d_in[4];
    const float* Wv = (const float*)d_in[5];
    const float* Wo = (const float*)d_in[6];
    const float* qnw = (const float*)d_in[7];
    const float* knw = (const float*)d_in[8];
    const float* lkA = (const float*)d_in[9];
    const float* lkB = (const float*)d_in[10];
    const float* lvA = (const float*)d_in[11];
    const float* lvB = (const float*)d_in[12];
    const float* skp = (const float*)d_in[13];
    const float* svp = (const float*)d_in[14];
    // d_in[15] = attention_mask: analytically causal, not read
    const float* cosb = (const float*)d_in[16];
    const float* sinb = (const float*)d_in[17];

    char* ws = (char*)d_ws;
    u16* hid_bf = (u16*)(ws);                    // 16 MB (reused as attn_out)
    u16* WqT    = (u16*)(ws + 16777216);         // 32 MB, contiguous with WkT/WvT: B' (6144 x 4096)
    u16* WkT    = (u16*)(ws + 50331648);         // 8 MB
    u16* WvT    = (u16*)(ws + 58720256);         // 8 MB
    u16* WoT    = (u16*)(ws + 67108864);         // 32 MB
    u16* qkv    = (u16*)(ws + 100663296);        // 24 MB (2048 x 6144)
    u16* qfin   = (u16*)(ws + 125829120);        // 16 MB (2048 x 4096)
    u16* kfull  = (u16*)(ws + 142606336);        // 4.125 MB (8 x 2112 x 128)
    u16* vt     = (u16*)(ws + 146931712);        // 4.125 MB (8 x 128 x 2112)
    u16* attn_o = hid_bf;                        // alias: hidden_bf dead after proj GEMM

    cvt_bf16_kernel<<<4096, 256, 0, stream>>>(hidden, hid_bf, 1048576);
    tcvt_kernel<<<dim3(128, 128), 256, 0, stream>>>(Wq, WqT, 4096, 4096);
    tcvt_kernel<<<dim3(128, 32), 256, 0, stream>>>(Wk, WkT, 4096, 1024);
    tcvt_kernel<<<dim3(128, 32), 256, 0, stream>>>(Wv, WvT, 4096, 1024);
    tcvt_kernel<<<dim3(128, 128), 256, 0, stream>>>(Wo, WoT, 4096, 4096);

    lora_kv_kernel<<<512, 128, 0, stream>>>(vkeys, vvals, lkA, lkB, lvA, lvB, skp, svp,
                                            kfull, vt);

    // fused QKV projection: (2048 x 4096) x (6144 x 4096)^T -> qkv (bf16)
    gemm_bt_kernel<0><<<dim3(16, 48), 256, 0, stream>>>(hid_bf, WqT, qkv, 2048, 6144, 4096, 6144);

    qnorm_rope_kernel<<<16384, 256, 0, stream>>>(qkv, qnw, cosb, sinb, qfin);
    kvnorm_rope_kernel<<<512, 256, 0, stream>>>(qkv, knw, cosb, sinb, kfull, vt);

    attn_kernel<<<512, 256, 0, stream>>>(qfin, kfull, vt, attn_o);

    // output projection: (2048 x 4096) x (4096 x 4096)^T -> d_out (f32)
    gemm_bt_kernel<1><<<dim3(16, 32), 256, 0, stream>>>(attn_o, WoT, d_out, 2048, 4096, 4096, 4096);
}